// Round 1
// baseline (875.171 us; speedup 1.0000x reference)
//
#include <hip/hip_runtime.h>
#include <hip/hip_bf16.h>

// Sizes: N=8, S=1024, EMB=1024, H=16, D=64, M=N*S=8192
// d_in: 0=value 1=key 2=query 3=mask(int32, N*S) 4=Wv 5=Wk 6=Wq 7=Wo 8=bo
// d_out: out (8388608 f32) ++ attention (134217728 f32)

typedef __bf16 bf16_t;
typedef __bf16 bf16x4 __attribute__((ext_vector_type(4)));
typedef __bf16 bf16x8 __attribute__((ext_vector_type(8)));
typedef float floatx4 __attribute__((ext_vector_type(4)));

#define MFMA16(a, b, c) __builtin_amdgcn_mfma_f32_16x16x32_bf16(a, b, c, 0, 0, 0)

__device__ __forceinline__ void gload16(const void* g, void* l) {
    __builtin_amdgcn_global_load_lds(
        (const __attribute__((address_space(1))) void*)g,
        (__attribute__((address_space(3))) void*)l, 16, 0, 0);
}

// ---------------- kernel 1: fp32 -> bf16 convert (q,k,v,Wq,Wk,Wv,Wo) ----------------
// dst layout (elements): [query 8388608][key 8388608][value 8388608][Wq 1048576][Wk][Wv][Wo]
__global__ __launch_bounds__(256) void convert_all(
    const float* __restrict__ q, const float* __restrict__ k, const float* __restrict__ v,
    const float* __restrict__ wq, const float* __restrict__ wk, const float* __restrict__ wv,
    const float* __restrict__ wo, bf16_t* __restrict__ dst)
{
    int tid = blockIdx.x * 256 + threadIdx.x;   // 0..7340031, each does 4 elements
    const float* src;
    int off;
    if (tid < 6291456) {
        int seg = tid >> 21;                    // 2097152 float4 per big segment
        src = (seg == 0) ? q : (seg == 1) ? k : v;
        off = (tid & 2097151) << 2;
    } else {
        int r = tid - 6291456;
        int seg = r >> 18;                      // 262144 float4 per weight
        src = (seg == 0) ? wq : (seg == 1) ? wk : (seg == 2) ? wv : wo;
        off = (r & 262143) << 2;
    }
    float4 x = *(const float4*)(src + off);
    bf16x4 o;
    o.x = (bf16_t)x.x; o.y = (bf16_t)x.y; o.z = (bf16_t)x.z; o.w = (bf16_t)x.w;
    *(bf16x4*)(dst + ((long)tid << 2)) = o;
}

// ---------------- kernel 2: projection GEMMs (C = X @ W^T), z selects q/k/v ----------------
// z=0: Q -> QH[nh][s][d]; z=1: K -> KH[nh][s][d]; z=2: V -> VT[nh][d][s] (transposed)
__global__ __launch_bounds__(256) void proj_gemm(
    const bf16_t* __restrict__ XQ, const bf16_t* __restrict__ XK, const bf16_t* __restrict__ XV,
    const bf16_t* __restrict__ WQ, const bf16_t* __restrict__ WK, const bf16_t* __restrict__ WV,
    bf16_t* __restrict__ QH, bf16_t* __restrict__ KH, bf16_t* __restrict__ VT)
{
    const int z = blockIdx.z;
    const bf16_t* X = (z == 0) ? XQ : (z == 1) ? XK : XV;
    const bf16_t* W = (z == 0) ? WQ : (z == 1) ? WK : WV;
    const int m0 = blockIdx.x * 128;
    const int n0 = blockIdx.y * 128;
    __shared__ bf16_t As[128 * 64];
    __shared__ bf16_t Bs[128 * 64];
    const int t = threadIdx.x;
    const int lane = t & 63, w = t >> 6;
    const int wm = w & 1, wn = w >> 1;
    const int quad = lane >> 4, l16 = lane & 15;
    floatx4 acc[4][4] = {};

    const bf16_t* Ag = X + (long)m0 * 1024;
    const bf16_t* Bg = W + (long)n0 * 1024;
    const int sr = t >> 3;            // 0..31
    const int sc = (t & 7) * 8;       // 0..56

    for (int k0 = 0; k0 < 1024; k0 += 64) {
        __syncthreads();
#pragma unroll
        for (int p = 0; p < 4; p++) {
            int row = p * 32 + sr;
            gload16(Ag + row * 1024 + k0 + sc, &As[p * 2048 + t * 8]);
            gload16(Bg + row * 1024 + k0 + sc, &Bs[p * 2048 + t * 8]);
        }
        __syncthreads();
#pragma unroll
        for (int kk = 0; kk < 2; kk++) {
            bf16x8 af[4], bfr[4];
#pragma unroll
            for (int i = 0; i < 4; i++)
                af[i] = *(const bf16x8*)&As[(wm * 64 + i * 16 + l16) * 64 + kk * 32 + quad * 8];
#pragma unroll
            for (int j = 0; j < 4; j++)
                bfr[j] = *(const bf16x8*)&Bs[(wn * 64 + j * 16 + l16) * 64 + kk * 32 + quad * 8];
#pragma unroll
            for (int i = 0; i < 4; i++)
#pragma unroll
                for (int j = 0; j < 4; j++)
                    acc[i][j] = MFMA16(af[i], bfr[j], acc[i][j]);
        }
    }
    // epilogue: C/D layout col=l16, row=quad*4+reg
#pragma unroll
    for (int i = 0; i < 4; i++) {
        int mrow0 = m0 + wm * 64 + i * 16 + quad * 4;
        int nidx = mrow0 >> 10, s = mrow0 & 1023;
#pragma unroll
        for (int j = 0; j < 4; j++) {
            int e = n0 + wn * 64 + j * 16 + l16;
            int h = e >> 6, d = e & 63;
            if (z == 2) {
                bf16x4 vv;
                vv.x = (bf16_t)acc[i][j][0]; vv.y = (bf16_t)acc[i][j][1];
                vv.z = (bf16_t)acc[i][j][2]; vv.w = (bf16_t)acc[i][j][3];
                *(bf16x4*)&VT[((nidx * 16 + h) * 64 + d) * 1024 + s] = vv;
            } else {
                bf16_t* dst = (z == 0) ? QH : KH;
                int base = ((nidx * 16 + h) * 1024 + s) * 64 + d;
                dst[base]       = (bf16_t)acc[i][j][0];
                dst[base + 64]  = (bf16_t)acc[i][j][1];
                dst[base + 128] = (bf16_t)acc[i][j][2];
                dst[base + 192] = (bf16_t)acc[i][j][3];
            }
        }
    }
}

// ---------------- kernel 3: attention per (head, 32-q-row chunk) ----------------
// scores 32x1024 in regs -> exact softmax -> write attention f32 -> PV via LDS P + Vt chunks
__global__ __launch_bounds__(512) void attn_kernel(
    const bf16_t* __restrict__ QH, const bf16_t* __restrict__ KH, const bf16_t* __restrict__ VT,
    const int* __restrict__ mask, float* __restrict__ att, bf16_t* __restrict__ O)
{
    const int nh = blockIdx.x;      // 0..127
    const int qc = blockIdx.y;      // 0..31
    const int nidx = nh >> 4, h = nh & 15;
    const int t = threadIdx.x;
    const int lane = t & 63, w = t >> 6;       // 8 waves
    const int rw = w & 1, wc = w >> 1;         // row-tile, col-group
    const int quad = lane >> 4, l16 = lane & 15;

    __shared__ bf16_t Qs[32 * 64];     // 4 KB
    __shared__ bf16_t Ks[128 * 64];    // 16 KB
    __shared__ bf16_t Vs[64 * 128];    // 16 KB
    __shared__ bf16_t Ps[32 * 136];    // 8.5 KB (padded stride vs bank conflicts)
    __shared__ float redm[4][32];
    __shared__ float reds[4][32];

    const bf16_t* Qg = QH + ((long)nh * 1024 + qc * 32) * 64;
    const bf16_t* Kg = KH + (long)nh * 1024 * 64;
    const bf16_t* Vg = VT + (long)nh * 64 * 1024;

    if (t < 256) gload16(Qg + t * 8, &Qs[t * 8]);

    // score accumulators: tile = kc*2+tt ; rows rw*16+quad*4+r, col kc*128+wc*32+tt*16+l16
    floatx4 sacc[16] = {};
    for (int kc = 0; kc < 8; kc++) {
        __syncthreads();
        gload16(Kg + kc * 8192 + t * 8, &Ks[t * 8]);
        gload16(Kg + kc * 8192 + 4096 + t * 8, &Ks[4096 + t * 8]);
        __syncthreads();
        bf16x8 qa[2];
        qa[0] = *(const bf16x8*)&Qs[(rw * 16 + l16) * 64 + quad * 8];
        qa[1] = *(const bf16x8*)&Qs[(rw * 16 + l16) * 64 + 32 + quad * 8];
#pragma unroll
        for (int tt = 0; tt < 2; tt++) {
#pragma unroll
            for (int kk = 0; kk < 2; kk++) {
                bf16x8 kb = *(const bf16x8*)&Ks[(wc * 32 + tt * 16 + l16) * 64 + kk * 32 + quad * 8];
                sacc[kc * 2 + tt] = MFMA16(qa[kk], kb, sacc[kc * 2 + tt]);
            }
        }
    }

    // ---- softmax stats (exact, two LDS reductions) ----
    const int* mrow = mask + nidx * 1024;
    float rm[4] = {-1e30f, -1e30f, -1e30f, -1e30f};
#pragma unroll
    for (int tile = 0; tile < 16; tile++) {
        int col = (tile >> 1) * 128 + wc * 32 + (tile & 1) * 16 + l16;
        int mk = mrow[col];
#pragma unroll
        for (int r = 0; r < 4; r++) {
            float e = sacc[tile][r] * 0.125f;          // /sqrt(HEAD_DIM)
            e = (mk != 0) ? e : -1e20f;
            sacc[tile][r] = e;
            rm[r] = fmaxf(rm[r], e);
        }
    }
#pragma unroll
    for (int d2 = 1; d2 < 16; d2 <<= 1)
#pragma unroll
        for (int r = 0; r < 4; r++) rm[r] = fmaxf(rm[r], __shfl_xor(rm[r], d2, 64));
    if (l16 == 0)
#pragma unroll
        for (int r = 0; r < 4; r++) redm[wc][rw * 16 + quad * 4 + r] = rm[r];
    __syncthreads();
#pragma unroll
    for (int r = 0; r < 4; r++) {
        int row = rw * 16 + quad * 4 + r;
        rm[r] = fmaxf(fmaxf(redm[0][row], redm[1][row]), fmaxf(redm[2][row], redm[3][row]));
    }
    float rs[4] = {0.f, 0.f, 0.f, 0.f};
#pragma unroll
    for (int tile = 0; tile < 16; tile++)
#pragma unroll
        for (int r = 0; r < 4; r++) {
            float ex = __expf(sacc[tile][r] - rm[r]);
            sacc[tile][r] = ex;                        // keep exp for PV phase
            rs[r] += ex;
        }
#pragma unroll
    for (int d2 = 1; d2 < 16; d2 <<= 1)
#pragma unroll
        for (int r = 0; r < 4; r++) rs[r] += __shfl_xor(rs[r], d2, 64);
    if (l16 == 0)
#pragma unroll
        for (int r = 0; r < 4; r++) reds[wc][rw * 16 + quad * 4 + r] = rs[r];
    __syncthreads();
    float invl[4];
#pragma unroll
    for (int r = 0; r < 4; r++) {
        int row = rw * 16 + quad * 4 + r;
        invl[r] = 1.0f / (reds[0][row] + reds[1][row] + reds[2][row] + reds[3][row]);
    }

    // ---- PV + attention write ----
    floatx4 oacc = {};
    float* attq = att + ((long)nh * 1024 + qc * 32) * 1024;
    for (int kc = 0; kc < 8; kc++) {
        __syncthreads();
        {
            int idx = t * 8;
            gload16(Vg + (idx >> 7) * 1024 + kc * 128 + (idx & 127), &Vs[idx]);
            idx = 4096 + t * 8;
            gload16(Vg + (idx >> 7) * 1024 + kc * 128 + (idx & 127), &Vs[idx]);
        }
#pragma unroll
        for (int tt = 0; tt < 2; tt++) {
            int tile = kc * 2 + tt;
            int colc = wc * 32 + tt * 16 + l16;
#pragma unroll
            for (int r = 0; r < 4; r++) {
                float p = sacc[tile][r] * invl[r];
                int qrow = rw * 16 + quad * 4 + r;
                attq[(long)qrow * 1024 + kc * 128 + colc] = p;
                Ps[qrow * 136 + colc] = (bf16_t)p;
            }
        }
        __syncthreads();
#pragma unroll
        for (int kk = 0; kk < 4; kk++) {
            bf16x8 pa = *(const bf16x8*)&Ps[(rw * 16 + l16) * 136 + kk * 32 + quad * 8];
            bf16x8 vb = *(const bf16x8*)&Vs[(wc * 16 + l16) * 128 + kk * 32 + quad * 8];
            oacc = MFMA16(pa, vb, oacc);
        }
    }
    // O[m][e], m=(n,s), e=h*64+d
#pragma unroll
    for (int r = 0; r < 4; r++) {
        int s = qc * 32 + rw * 16 + quad * 4 + r;
        long m = (long)nidx * 1024 + s;
        O[m * 1024 + h * 64 + wc * 16 + l16] = (bf16_t)oacc[r];
    }
}

// ---------------- kernel 4: out = O @ Wo^T + bo (f32 out) ----------------
__global__ __launch_bounds__(256) void out_gemm(
    const bf16_t* __restrict__ O, const bf16_t* __restrict__ WO,
    const float* __restrict__ bo, float* __restrict__ out)
{
    const int m0 = blockIdx.x * 128;
    const int n0 = blockIdx.y * 128;
    __shared__ bf16_t As[128 * 64];
    __shared__ bf16_t Bs[128 * 64];
    const int t = threadIdx.x;
    const int lane = t & 63, w = t >> 6;
    const int wm = w & 1, wn = w >> 1;
    const int quad = lane >> 4, l16 = lane & 15;
    floatx4 acc[4][4] = {};

    const bf16_t* Ag = O + (long)m0 * 1024;
    const bf16_t* Bg = WO + (long)n0 * 1024;
    const int sr = t >> 3;
    const int sc = (t & 7) * 8;

    for (int k0 = 0; k0 < 1024; k0 += 64) {
        __syncthreads();
#pragma unroll
        for (int p = 0; p < 4; p++) {
            int row = p * 32 + sr;
            gload16(Ag + row * 1024 + k0 + sc, &As[p * 2048 + t * 8]);
            gload16(Bg + row * 1024 + k0 + sc, &Bs[p * 2048 + t * 8]);
        }
        __syncthreads();
#pragma unroll
        for (int kk = 0; kk < 2; kk++) {
            bf16x8 af[4], bfr[4];
#pragma unroll
            for (int i = 0; i < 4; i++)
                af[i] = *(const bf16x8*)&As[(wm * 64 + i * 16 + l16) * 64 + kk * 32 + quad * 8];
#pragma unroll
            for (int j = 0; j < 4; j++)
                bfr[j] = *(const bf16x8*)&Bs[(wn * 64 + j * 16 + l16) * 64 + kk * 32 + quad * 8];
#pragma unroll
            for (int i = 0; i < 4; i++)
#pragma unroll
                for (int j = 0; j < 4; j++)
                    acc[i][j] = MFMA16(af[i], bfr[j], acc[i][j]);
        }
    }
#pragma unroll
    for (int i = 0; i < 4; i++) {
        int mrow0 = m0 + wm * 64 + i * 16 + quad * 4;
#pragma unroll
        for (int j = 0; j < 4; j++) {
            int e = n0 + wn * 64 + j * 16 + l16;
            float b = bo[e];
#pragma unroll
            for (int r = 0; r < 4; r++)
                out[(long)(mrow0 + r) * 1024 + e] = acc[i][j][r] + b;
        }
    }
}

// ---------------- launch ----------------
extern "C" void kernel_launch(void* const* d_in, const int* in_sizes, int n_in,
                              void* d_out, int out_size, void* d_ws, size_t ws_size,
                              hipStream_t stream) {
    (void)in_sizes; (void)n_in; (void)out_size; (void)ws_size;
    const float* value = (const float*)d_in[0];
    const float* key   = (const float*)d_in[1];
    const float* query = (const float*)d_in[2];
    const int*   mask  = (const int*)d_in[3];
    const float* Wv    = (const float*)d_in[4];
    const float* Wk    = (const float*)d_in[5];
    const float* Wq    = (const float*)d_in[6];
    const float* Wo    = (const float*)d_in[7];
    const float* bo    = (const float*)d_in[8];
    float* out = (float*)d_out;
    float* att = out + 8388608;

    char* ws = (char*)d_ws;
    // ws map (bytes): XQ 0, XK 16M, XV 32M, WQ 48M.., QH/KH/VT after, O reuses XQ (dead)
    bf16_t* XQ = (bf16_t*)(ws + 0);
    bf16_t* XK = (bf16_t*)(ws + 16777216);
    bf16_t* XV = (bf16_t*)(ws + 33554432);
    bf16_t* WQb = (bf16_t*)(ws + 50331648);
    bf16_t* WKb = (bf16_t*)(ws + 52428800);
    bf16_t* WVb = (bf16_t*)(ws + 54525952);
    bf16_t* WOb = (bf16_t*)(ws + 56623104);
    bf16_t* QH = (bf16_t*)(ws + 58720256);
    bf16_t* KH = (bf16_t*)(ws + 75497472);
    bf16_t* VT = (bf16_t*)(ws + 92274688);
    bf16_t* OB = (bf16_t*)(ws + 0);   // reuse XQ region (dead after proj_gemm)

    convert_all<<<28672, 256, 0, stream>>>(query, key, value, Wq, Wk, Wv, Wo, XQ);
    proj_gemm<<<dim3(64, 8, 3), 256, 0, stream>>>(XQ, XK, XV, WQb, WKb, WVb, QH, KH, VT);
    attn_kernel<<<dim3(128, 32), 512, 0, stream>>>(QH, KH, VT, mask, att, OB);
    out_gemm<<<dim3(64, 8), 256, 0, stream>>>(OB, WOb, bo, out);
}